// Round 11
// baseline (188.900 us; speedup 1.0000x reference)
//
#include <hip/hip_runtime.h>

#define B_ 2
#define L_ 256
#define H_ 256
#define A_ 32
#define P_ 64
#define PSTR 76    // posT LDS row stride (floats)
#define TSTR 516   // out-tile LDS row stride (floats): 8*64 + 4
#define XSTR 260   // x/in_w LDS row stride (floats): 16B-aligned, bank-spread

typedef __bf16 bf16x8 __attribute__((ext_vector_type(8)));
typedef float  f32x4  __attribute__((ext_vector_type(4)));

// k1: 512 blocks = 64 row-groups (8 rows) x 8 p-eighths. reps = diagnostic repeat.
__global__ __launch_bounds__(256) void k1_proj(
    const float* __restrict__ x,     // [B,L,H]
    const float* __restrict__ in_w,  // [A,H]
    const float* __restrict__ in_b,  // [A]
    const float* __restrict__ out_w, // [P, A*A]
    __bf16* __restrict__ gb,         // [B*L][P][A] bf16
    __bf16* __restrict__ hb,         // [B*L][A]   bf16
    int reps)
{
    __shared__ float xs[8][XSTR];
    __shared__ float ws[32][XSTR];
    __shared__ float hl[8][A_];

    const int t = threadIdx.x;
    const int rowg = blockIdx.x >> 3;     // 0..63
    const int pe   = blockIdx.x & 7;      // p-eighth
    const int r0 = rowg * 8;              // flat row base (b*L+l)

    for (int rep = 0; rep < reps; ++rep) {

    #pragma unroll
    for (int u = t; u < 512; u += 256) {
        const int row = u >> 6, c4 = u & 63;
        *(float4*)&xs[row][c4 * 4] = ((const float4*)(x + (size_t)(r0 + row) * H_))[c4];
    }
    #pragma unroll
    for (int u = t; u < 2048; u += 256) {
        const int a = u >> 6, c4 = u & 63;
        *(float4*)&ws[a][c4 * 4] = ((const float4*)(in_w + (size_t)a * H_))[c4];
    }
    __syncthreads();

    {   // h: thread t -> row t>>5, a t&31; full 256-dot from LDS
        const int row = t >> 5, a = t & 31;
        float s = 0.f;
        #pragma unroll
        for (int c4 = 0; c4 < 64; ++c4) {
            const float4 xv = *(const float4*)&xs[row][c4 * 4];
            const float4 wv = *(const float4*)&ws[a][c4 * 4];
            s += xv.x * wv.x + xv.y * wv.y + xv.z * wv.z + xv.w * wv.w;
        }
        const float hv = s + in_b[a];
        hl[row][a] = hv;
        if (pe == 0) hb[(size_t)(r0 + row) * A_ + a] = (__bf16)hv;
    }
    __syncthreads();

    {   // g: thread t -> p = pe*8 + (t>>5), a = t&31; 8 j-rows
        const int p = pe * 8 + (t >> 5);
        const int a = t & 31;
        const float4* wrow = (const float4*)(out_w + (size_t)p * (A_ * A_) + a * A_);
        float4 w[8];
        #pragma unroll
        for (int m = 0; m < 8; ++m) w[m] = wrow[m];
        float sac[8];
        #pragma unroll
        for (int jj = 0; jj < 8; ++jj) {
            const float4* hh = (const float4*)hl[jj];   // uniform -> broadcast
            float s = 0.f;
            #pragma unroll
            for (int m = 0; m < 8; ++m) {
                const float4 h4 = hh[m];
                s += w[m].x * h4.x + w[m].y * h4.y + w[m].z * h4.z + w[m].w * h4.w;
            }
            sac[jj] = s;
        }
        #pragma unroll
        for (int jj = 0; jj < 8; ++jj)
            gb[((size_t)(r0 + jj) * P_ + p) * A_ + a] = (__bf16)sac[jj];
    }
    __syncthreads();
    }
}

// k2: 1024 blocks: 16i x 8j x 64p; mfma(A=g,B=h) -> D[m=p][n=i]; LDS-staged
// linear NT epilogue. reps = diagnostic repeat.
__global__ __launch_bounds__(256) void k2_mfma(
    const __bf16* __restrict__ gb,   // [B*L][P][A]
    const __bf16* __restrict__ hb,   // [B*L][A]
    const float* __restrict__ out_b, // [P]
    const float* __restrict__ pos_w, // [P,17]
    const float* __restrict__ pos_b, // [P]
    float* __restrict__ out,         // [B,L,L,P]
    int reps)
{
    __shared__ float posT[17 * PSTR];
    __shared__ float tile[16][TSTR];
    const int t = threadIdx.x;

    for (int rep = 0; rep < reps; ++rep) {

    for (int e = t; e < 17 * P_; e += 256) {
        const int d = e >> 6, p = e & 63;
        posT[d * PSTR + p] = pos_w[p * 17 + d] + pos_b[p] + out_b[p];
    }
    __syncthreads();

    const int lane = t & 63;
    const int w = t >> 6;            // wave 0..3
    const int j0 = blockIdx.x * 8;
    const int i0 = blockIdx.y * 16;
    const int b = blockIdx.z;

    const int l15 = lane & 15;
    const int hi = lane >> 4;        // 0..3
    const int i = i0 + l15;
    const int p_r0 = hi * 4;         // p offset within 16-p group

    const bf16x8 hfrag = *(const bf16x8*)(hb + ((size_t)(b * L_ + i)) * A_ + hi * 8);
    const f32x4 zero = {0.f, 0.f, 0.f, 0.f};

    #pragma unroll
    for (int tj = 0; tj < 2; ++tj) {
        const int jl = w * 2 + tj;   // local j 0..7
        const int j = j0 + jl;
        const __bf16* gr = gb + ((size_t)(b * L_ + j)) * (P_ * A_);

        bf16x8 gfrag[4];
        #pragma unroll
        for (int pg = 0; pg < 4; ++pg)
            gfrag[pg] = *(const bf16x8*)(gr + (pg * 16 + l15) * A_ + hi * 8);

        f32x4 acc[4];
        #pragma unroll
        for (int pg = 0; pg < 4; ++pg)
            acc[pg] = __builtin_amdgcn_mfma_f32_16x16x32_bf16(gfrag[pg], hfrag, zero, 0, 0, 0);

        int d = i - j;
        d = d < -8 ? -8 : (d > 8 ? 8 : d);
        d += 8;

        #pragma unroll
        for (int pg = 0; pg < 4; ++pg) {
            const f32x4 pe = *(const f32x4*)(posT + d * PSTR + pg * 16 + p_r0);
            *(f32x4*)&tile[l15][jl * 64 + pg * 16 + p_r0] = acc[pg] + pe;
        }
    }
    __syncthreads();

    {
        const int ir = t >> 4;           // 0..15
        const int c  = t & 15;           // 0..15
        float* orow = out + (((size_t)(b * L_ + i0 + ir)) * L_ + blockIdx.x * 8) * P_;
        #pragma unroll
        for (int m = 0; m < 8; ++m) {
            const int f4 = m * 16 + c;
            const f32x4 v = *(const f32x4*)&tile[ir][f4 * 4];
            __builtin_nontemporal_store(v, (f32x4*)(orow + f4 * 4));
        }
    }
    __syncthreads();
    }
}

extern "C" void kernel_launch(void* const* d_in, const int* in_sizes, int n_in,
                              void* d_out, int out_size, void* d_ws, size_t ws_size,
                              hipStream_t stream) {
    const float* x     = (const float*)d_in[0];
    const float* in_w  = (const float*)d_in[1];
    const float* in_b  = (const float*)d_in[2];
    const float* out_w = (const float*)d_in[3];
    const float* out_b = (const float*)d_in[4];
    const float* pos_w = (const float*)d_in[5];
    const float* pos_b = (const float*)d_in[6];
    float* out = (float*)d_out;

    __bf16* gb = (__bf16*)d_ws;                                   // 2 MB
    __bf16* hb = gb + (size_t)B_ * L_ * P_ * A_;                  // +32 KB

    // normal pipeline (the real candidate, = R9)
    k1_proj<<<dim3(512), 256, 0, stream>>>(x, in_w, in_b, out_w, gb, hb, 1);
    k2_mfma<<<dim3(L_ / 8, L_ / 16, B_), 256, 0, stream>>>(gb, hb, out_b, pos_w, pos_b, out, 1);

    // diagnostic heavies: idempotent (rewrite identical values), sized to
    // exceed the ~41us fills so they surface in rocprof top-5 with full PMCs.
    k1_proj<<<dim3(512), 256, 0, stream>>>(x, in_w, in_b, out_w, gb, hb, 24);
    k2_mfma<<<dim3(L_ / 8, L_ / 16, B_), 256, 0, stream>>>(gb, hb, out_b, pos_w, pos_b, out, 12);
}

// Round 12
// 25.616 us; speedup vs baseline: 7.3743x; 7.3743x over previous
//
#include <hip/hip_runtime.h>

#define B_ 2
#define L_ 256
#define H_ 256
#define A_ 32
#define P_ 64
#define PSTR 76    // posT LDS row stride (floats)
#define TSTR 516   // out-tile LDS row stride (floats): 8*64 + 4

typedef __bf16 bf16x8 __attribute__((ext_vector_type(8)));
typedef float  f32x4  __attribute__((ext_vector_type(4)));

// k1a: h only. 256 blocks x 2 rows; 4 threads per 256-dot (R6-proven form).
// Writes hf (f32, consumed by k1b) and hb (bf16, MFMA B-operand for k2).
__global__ __launch_bounds__(256) void k1a_h(
    const float* __restrict__ x,     // [B,L,H]
    const float* __restrict__ in_w,  // [A,H]
    const float* __restrict__ in_b,  // [A]
    float* __restrict__ hf,          // [B*L][A] f32
    __bf16* __restrict__ hb)         // [B*L][A] bf16
{
    __shared__ float xs[2 * H_];
    const int t = threadIdx.x;
    const int r0 = blockIdx.x * 2;

    if (t < 128) ((float4*)xs)[t] = ((const float4*)(x + (size_t)r0 * H_))[t];
    __syncthreads();

    const int jj = t >> 7;        // row 0..1
    const int rem = t & 127;
    const int a = rem >> 2;       // 0..31
    const int q = rem & 3;        // quarter of the 256-dot
    const float4* w4 = (const float4*)(in_w + a * H_ + q * 64);
    const float4* xv4 = (const float4*)(xs + jj * H_ + q * 64);
    float s = 0.f;
    #pragma unroll
    for (int m = 0; m < 16; ++m) {
        float4 w = w4[m], xv = xv4[m];
        s += w.x * xv.x + w.y * xv.y + w.z * xv.z + w.w * xv.w;
    }
    s += __shfl_xor(s, 1);
    s += __shfl_xor(s, 2);
    if (q == 0) {
        const float hv = s + in_b[a];
        hf[(size_t)(r0 + jj) * A_ + a] = hv;
        hb[(size_t)(r0 + jj) * A_ + a] = (__bf16)hv;
    }
}

// k1b: g only. 512 blocks = 64 row-groups (8 rows) x 8 p-octets.
// Tiny LDS (h rows, 1.2 KB) -> no occupancy cap; thread owns a p-PAIR so each
// broadcast ds_read of h feeds 8 FMAs. g[r,a,p] = sum_c out_w[p,a*32+c]*h[r,c],
// f32 (same order as R9), rounded bf16, stored transposed gb[r][p][a].
__global__ __launch_bounds__(256) void k1b_g(
    const float* __restrict__ hf,    // [B*L][A]
    const float* __restrict__ out_w, // [P, A*A]
    __bf16* __restrict__ gb)         // [B*L][P][A]
{
    __shared__ float hl[8][36];
    const int t = threadIdx.x;
    const int rowg = blockIdx.x >> 3;     // 0..63
    const int pq   = blockIdx.x & 7;      // p-octet
    const int r0 = rowg * 8;
    const int p0 = pq * 8;

    if (t < 64) {
        const int row = t >> 3, seg = t & 7;
        *(float4*)&hl[row][seg * 4] = ((const float4*)(hf + (size_t)(r0 + row) * A_))[seg];
    }
    __syncthreads();

    const int a = t & 31;
    const int slot = t >> 5;      // 0..7
    const int pair = slot & 3;    // p-pair index
    const int jh = slot >> 2;     // j-half: rows jh*4 .. +3
    const int pA = p0 + pair * 2;
    const int pB = pA + 1;

    float4 wA[8], wB[8];
    {
        const float4* ra = (const float4*)(out_w + (size_t)pA * (A_ * A_) + a * A_);
        const float4* rb = (const float4*)(out_w + (size_t)pB * (A_ * A_) + a * A_);
        #pragma unroll
        for (int m = 0; m < 8; ++m) { wA[m] = ra[m]; wB[m] = rb[m]; }
    }

    #pragma unroll
    for (int jj = 0; jj < 4; ++jj) {
        const int row = jh * 4 + jj;
        float sA = 0.f, sB = 0.f;
        #pragma unroll
        for (int m = 0; m < 8; ++m) {
            const float4 h4 = *(const float4*)&hl[row][m * 4];  // uniform -> broadcast
            sA += wA[m].x * h4.x + wA[m].y * h4.y + wA[m].z * h4.z + wA[m].w * h4.w;
            sB += wB[m].x * h4.x + wB[m].y * h4.y + wB[m].z * h4.z + wB[m].w * h4.w;
        }
        const size_t rbase = (size_t)(r0 + row) * P_;
        gb[(rbase + pA) * A_ + a] = (__bf16)sA;
        gb[(rbase + pB) * A_ + a] = (__bf16)sB;
    }
}

// k2: unchanged R9/R6 measured-best. out[b,i,j,p] = sum_a g[j,a,p] h[i,a] via
// mfma(A=g, B=h): D[m=p][n=i]; 16i x 8j x 64p tiles; LDS-staged fused epilogue,
// linear NT readout.
__global__ __launch_bounds__(256) void k2_mfma(
    const __bf16* __restrict__ gb,   // [B*L][P][A]
    const __bf16* __restrict__ hb,   // [B*L][A]
    const float* __restrict__ out_b, // [P]
    const float* __restrict__ pos_w, // [P,17]
    const float* __restrict__ pos_b, // [P]
    float* __restrict__ out)         // [B,L,L,P]
{
    __shared__ float posT[17 * PSTR];
    __shared__ float tile[16][TSTR];
    const int t = threadIdx.x;

    for (int e = t; e < 17 * P_; e += 256) {
        const int d = e >> 6, p = e & 63;
        posT[d * PSTR + p] = pos_w[p * 17 + d] + pos_b[p] + out_b[p];
    }
    __syncthreads();

    const int lane = t & 63;
    const int w = t >> 6;            // wave 0..3
    const int j0 = blockIdx.x * 8;
    const int i0 = blockIdx.y * 16;
    const int b = blockIdx.z;

    const int l15 = lane & 15;
    const int hi = lane >> 4;        // 0..3
    const int i = i0 + l15;
    const int p_r0 = hi * 4;

    const bf16x8 hfrag = *(const bf16x8*)(hb + ((size_t)(b * L_ + i)) * A_ + hi * 8);
    const f32x4 zero = {0.f, 0.f, 0.f, 0.f};

    #pragma unroll
    for (int tj = 0; tj < 2; ++tj) {
        const int jl = w * 2 + tj;   // local j 0..7
        const int j = j0 + jl;
        const __bf16* gr = gb + ((size_t)(b * L_ + j)) * (P_ * A_);

        bf16x8 gfrag[4];
        #pragma unroll
        for (int pg = 0; pg < 4; ++pg)
            gfrag[pg] = *(const bf16x8*)(gr + (pg * 16 + l15) * A_ + hi * 8);

        f32x4 acc[4];
        #pragma unroll
        for (int pg = 0; pg < 4; ++pg)
            acc[pg] = __builtin_amdgcn_mfma_f32_16x16x32_bf16(gfrag[pg], hfrag, zero, 0, 0, 0);

        int d = i - j;
        d = d < -8 ? -8 : (d > 8 ? 8 : d);
        d += 8;

        #pragma unroll
        for (int pg = 0; pg < 4; ++pg) {
            const f32x4 pe = *(const f32x4*)(posT + d * PSTR + pg * 16 + p_r0);
            *(f32x4*)&tile[l15][jl * 64 + pg * 16 + p_r0] = acc[pg] + pe;
        }
    }
    __syncthreads();

    const int ir = t >> 4;           // 0..15
    const int c  = t & 15;           // 0..15
    float* orow = out + (((size_t)(b * L_ + i0 + ir)) * L_ + j0) * P_;
    #pragma unroll
    for (int m = 0; m < 8; ++m) {
        const int f4 = m * 16 + c;
        const f32x4 v = *(const f32x4*)&tile[ir][f4 * 4];
        __builtin_nontemporal_store(v, (f32x4*)(orow + f4 * 4));
    }
}

extern "C" void kernel_launch(void* const* d_in, const int* in_sizes, int n_in,
                              void* d_out, int out_size, void* d_ws, size_t ws_size,
                              hipStream_t stream) {
    const float* x     = (const float*)d_in[0];
    const float* in_w  = (const float*)d_in[1];
    const float* in_b  = (const float*)d_in[2];
    const float* out_w = (const float*)d_in[3];
    const float* out_b = (const float*)d_in[4];
    const float* pos_w = (const float*)d_in[5];
    const float* pos_b = (const float*)d_in[6];
    float* out = (float*)d_out;

    __bf16* gb = (__bf16*)d_ws;                                     // 2 MB
    __bf16* hb = gb + (size_t)B_ * L_ * P_ * A_;                    // +32 KB
    float*  hf = (float*)(hb + (size_t)B_ * L_ * A_);               // +64 KB

    k1a_h<<<dim3(B_ * L_ / 2), 256, 0, stream>>>(x, in_w, in_b, hf, hb);
    k1b_g<<<dim3(512), 256, 0, stream>>>(hf, out_w, gb);
    k2_mfma<<<dim3(L_ / 8, L_ / 16, B_), 256, 0, stream>>>(gb, hb, out_b, pos_w, pos_b, out);
}

// Round 13
// 22.815 us; speedup vs baseline: 8.2797x; 1.1228x over previous
//
#include <hip/hip_runtime.h>

#define B_ 2
#define L_ 256
#define H_ 256
#define A_ 32
#define P_ 64
#define PSTR 76    // posT LDS row stride (floats)
#define TSTR 516   // out-tile LDS row stride (floats): 8*64 + 4
#define XSTR 260   // x LDS row stride (floats)

typedef __bf16 bf16x8 __attribute__((ext_vector_type(8)));
typedef float  f32x4  __attribute__((ext_vector_type(4)));

// k1: 512 blocks = 64 row-groups (8 rows) x 8 p-octets.
// h-phase: in_w QUARTERS live in VGPRs (global L2 loads), x via LDS broadcast
//   -> DS-pipe work cut ~3x vs R9 (which read both operands from LDS).
//   Thread (a=t&31, r4=(t>>5)&1, q=t>>6): 4 rows x 64-c quarter-dot;
//   q-partials reduced through LDS in fixed order (deterministic).
// g-phase: unchanged R9 (p = pe*8 + t>>5, a = t&31, 8 j-rows, hl broadcast).
__global__ __launch_bounds__(256) void k1_proj(
    const float* __restrict__ x,     // [B,L,H]
    const float* __restrict__ in_w,  // [A,H]
    const float* __restrict__ in_b,  // [A]
    const float* __restrict__ out_w, // [P, A*A]
    __bf16* __restrict__ gb,         // [B*L][P][A] bf16
    __bf16* __restrict__ hb)         // [B*L][A]   bf16
{
    __shared__ float xs[8][XSTR];
    __shared__ float hp[4][8][33];   // q-partials
    __shared__ float hl[8][36];      // reduced h rows (f32)

    const int t = threadIdx.x;
    const int rowg = blockIdx.x >> 3;     // 0..63
    const int pe   = blockIdx.x & 7;      // p-octet
    const int r0 = rowg * 8;

    // stage x: 8 rows x 64 f4
    #pragma unroll
    for (int u = t; u < 512; u += 256) {
        const int row = u >> 6, c4 = u & 63;
        *(float4*)&xs[row][c4 * 4] = ((const float4*)(x + (size_t)(r0 + row) * H_))[c4];
    }
    __syncthreads();

    // h-phase
    {
        const int a  = t & 31;
        const int r4 = (t >> 5) & 1;      // rows r4*4 .. +3
        const int q  = t >> 6;            // quarter 0..3 (one q per wave)
        float4 wq[16];
        const float4* wr = (const float4*)(in_w + (size_t)a * H_ + q * 64);
        #pragma unroll
        for (int m = 0; m < 16; ++m) wq[m] = wr[m];

        float s0 = 0.f, s1 = 0.f, s2 = 0.f, s3 = 0.f;
        #pragma unroll
        for (int m = 0; m < 16; ++m) {
            const float4 w = wq[m];
            const float4 x0 = *(const float4*)&xs[r4 * 4 + 0][q * 64 + m * 4];
            const float4 x1 = *(const float4*)&xs[r4 * 4 + 1][q * 64 + m * 4];
            const float4 x2 = *(const float4*)&xs[r4 * 4 + 2][q * 64 + m * 4];
            const float4 x3 = *(const float4*)&xs[r4 * 4 + 3][q * 64 + m * 4];
            s0 += w.x * x0.x + w.y * x0.y + w.z * x0.z + w.w * x0.w;
            s1 += w.x * x1.x + w.y * x1.y + w.z * x1.z + w.w * x1.w;
            s2 += w.x * x2.x + w.y * x2.y + w.z * x2.z + w.w * x2.w;
            s3 += w.x * x3.x + w.y * x3.y + w.z * x3.z + w.w * x3.w;
        }
        hp[q][r4 * 4 + 0][a] = s0;
        hp[q][r4 * 4 + 1][a] = s1;
        hp[q][r4 * 4 + 2][a] = s2;
        hp[q][r4 * 4 + 3][a] = s3;
    }
    __syncthreads();

    // reduce q-partials: thread (row = t>>5, a = t&31)
    {
        const int row = t >> 5, a = t & 31;
        const float hv = ((hp[0][row][a] + hp[1][row][a]) +
                          (hp[2][row][a] + hp[3][row][a])) + in_b[a];
        hl[row][a] = hv;
        if (pe == 0) hb[(size_t)(r0 + row) * A_ + a] = (__bf16)hv;
    }
    __syncthreads();

    // g-phase (R9-identical): thread owns p = pe*8 + (t>>5), a = t&31
    {
        const int p = pe * 8 + (t >> 5);
        const int a = t & 31;
        const float4* wrow = (const float4*)(out_w + (size_t)p * (A_ * A_) + a * A_);
        float4 w[8];
        #pragma unroll
        for (int m = 0; m < 8; ++m) w[m] = wrow[m];
        float sac[8];
        #pragma unroll
        for (int jj = 0; jj < 8; ++jj) {
            float s = 0.f;
            #pragma unroll
            for (int m = 0; m < 8; ++m) {
                const float4 h4 = *(const float4*)&hl[jj][m * 4];   // uniform -> broadcast
                s += w[m].x * h4.x + w[m].y * h4.y + w[m].z * h4.z + w[m].w * h4.w;
            }
            sac[jj] = s;
        }
        #pragma unroll
        for (int jj = 0; jj < 8; ++jj)
            gb[((size_t)(r0 + jj) * P_ + p) * A_ + a] = (__bf16)sac[jj];
    }
}

// k2: R9-identical body, but 512 blocks (16 jt x 16 it x 2 b), each covering
// TWO 8-j subtiles serially -> halves dispatch ramp, same work & occupancy.
__global__ __launch_bounds__(256) void k2_mfma(
    const __bf16* __restrict__ gb,   // [B*L][P][A]
    const __bf16* __restrict__ hb,   // [B*L][A]
    const float* __restrict__ out_b, // [P]
    const float* __restrict__ pos_w, // [P,17]
    const float* __restrict__ pos_b, // [P]
    float* __restrict__ out)         // [B,L,L,P]
{
    __shared__ float posT[17 * PSTR];
    __shared__ float tile[16][TSTR];
    const int t = threadIdx.x;

    for (int e = t; e < 17 * P_; e += 256) {
        const int d = e >> 6, p = e & 63;
        posT[d * PSTR + p] = pos_w[p * 17 + d] + pos_b[p] + out_b[p];
    }

    const int lane = t & 63;
    const int w = t >> 6;            // wave 0..3
    const int i0 = blockIdx.y * 16;
    const int b = blockIdx.z;

    const int l15 = lane & 15;
    const int hi = lane >> 4;        // 0..3
    const int i = i0 + l15;
    const int p_r0 = hi * 4;

    const bf16x8 hfrag = *(const bf16x8*)(hb + ((size_t)(b * L_ + i)) * A_ + hi * 8);
    const f32x4 zero = {0.f, 0.f, 0.f, 0.f};
    __syncthreads();                 // posT ready

    #pragma unroll
    for (int sub = 0; sub < 2; ++sub) {
        const int j0 = (blockIdx.x * 2 + sub) * 8;

        #pragma unroll
        for (int tj = 0; tj < 2; ++tj) {
            const int jl = w * 2 + tj;   // local j 0..7
            const int j = j0 + jl;
            const __bf16* gr = gb + ((size_t)(b * L_ + j)) * (P_ * A_);

            bf16x8 gfrag[4];
            #pragma unroll
            for (int pg = 0; pg < 4; ++pg)
                gfrag[pg] = *(const bf16x8*)(gr + (pg * 16 + l15) * A_ + hi * 8);

            f32x4 acc[4];
            #pragma unroll
            for (int pg = 0; pg < 4; ++pg)
                acc[pg] = __builtin_amdgcn_mfma_f32_16x16x32_bf16(gfrag[pg], hfrag, zero, 0, 0, 0);

            int d = i - j;
            d = d < -8 ? -8 : (d > 8 ? 8 : d);
            d += 8;

            #pragma unroll
            for (int pg = 0; pg < 4; ++pg) {
                const f32x4 pe = *(const f32x4*)(posT + d * PSTR + pg * 16 + p_r0);
                *(f32x4*)&tile[l15][jl * 64 + pg * 16 + p_r0] = acc[pg] + pe;
            }
        }
        __syncthreads();

        {   // linear readout: row ir = 512 consecutive floats
            const int ir = t >> 4;
            const int c  = t & 15;
            float* orow = out + (((size_t)(b * L_ + i0 + ir)) * L_ + j0) * P_;
            #pragma unroll
            for (int m = 0; m < 8; ++m) {
                const int f4 = m * 16 + c;
                const f32x4 v = *(const f32x4*)&tile[ir][f4 * 4];
                __builtin_nontemporal_store(v, (f32x4*)(orow + f4 * 4));
            }
        }
        __syncthreads();
    }
}

extern "C" void kernel_launch(void* const* d_in, const int* in_sizes, int n_in,
                              void* d_out, int out_size, void* d_ws, size_t ws_size,
                              hipStream_t stream) {
    const float* x     = (const float*)d_in[0];
    const float* in_w  = (const float*)d_in[1];
    const float* in_b  = (const float*)d_in[2];
    const float* out_w = (const float*)d_in[3];
    const float* out_b = (const float*)d_in[4];
    const float* pos_w = (const float*)d_in[5];
    const float* pos_b = (const float*)d_in[6];
    float* out = (float*)d_out;

    __bf16* gb = (__bf16*)d_ws;                                   // 2 MB
    __bf16* hb = gb + (size_t)B_ * L_ * P_ * A_;                  // +32 KB

    k1_proj<<<dim3(512), 256, 0, stream>>>(x, in_w, in_b, out_w, gb, hb);
    k2_mfma<<<dim3(16, 16, B_), 256, 0, stream>>>(gb, hb, out_b, pos_w, pos_b, out);
}